// Round 5
// baseline (65.765 us; speedup 1.0000x reference)
//
#include <hip/hip_runtime.h>

// SO3SelfInteraction: y[a,k,f] = sum_e Wcg[e] * x[a,i1[e],f] * x[a,i2[e],f]
// LMAX=2 -> S=9, N_ATOMS=32000, N_FEAT=128.
//
// R4 change vs R3 (single experiment):
//  - y stores emitted as inline-asm `global_store_dwordx4 ... sc0 sc1 nt`
//    (system-scope, non-temporal): goal is NO allocation of the y write
//    stream in L2/Infinity-Cache, so x (147.5 MB) stays fully L3-resident
//    across graph replays (R3 counters: FETCH=72MB -> y evicts half of x
//    every replay; __builtin_nontemporal_store did not prevent allocation).
//  - everything else identical to R3 (W[45][12] prep, straight-line 45-pair
//    unroll, register-resident xv/acc).

#define S9 9
#define NFEAT 128
#define THREADS 256
#define NPAIR 45
#define WSTRIDE 12   // padded floats per pair row

typedef float f4 __attribute__((ext_vector_type(4)));

__global__ void so3_prep_kernel(const float* __restrict__ weight,
                                const float* __restrict__ cg_vals,
                                const int* __restrict__ idx_1,
                                const int* __restrict__ idx_2,
                                const int* __restrict__ idx_out,
                                const int* __restrict__ widx_1,
                                const int* __restrict__ widx_2,
                                int nnz, float* __restrict__ W) {
    __shared__ float d[NPAIR * WSTRIDE];
    const int tid = threadIdx.x;

    for (int i = tid; i < NPAIR * WSTRIDE; i += THREADS) d[i] = 0.f;
    __syncthreads();

    for (int e = tid; e < nnz; e += THREADS) {
        const int i = idx_1[e];
        const int j = idx_2[e];
        const int k = idx_out[e];
        const float w = weight[widx_1[e] * 3 + widx_2[e]] * cg_vals[e];
        const int a = min(i, j);
        const int b = max(i, j);
        const int p = a * 9 - a * (a - 1) / 2 + (b - a);
        // <=2 adds per cell ((i,j),(j,i)); fp add commutative -> deterministic
        atomicAdd(&d[p * WSTRIDE + k], w);
    }
    __syncthreads();

    for (int i = tid; i < NPAIR * WSTRIDE; i += THREADS) W[i] = d[i];
}

__device__ __forceinline__ void stream_store_f4(float* p, f4 v) {
    // system-scope non-temporal store: do not allocate in L2/MALL
    asm volatile("global_store_dwordx4 %0, %1, off sc0 sc1 nt"
                 :: "v"(p), "v"(v) : "memory");
}

__global__ __launch_bounds__(THREADS) void so3_main_kernel(
        const float* __restrict__ x,
        const float* __restrict__ W,
        float* __restrict__ y) {
    static constexpr int PA[NPAIR] = {
        0,0,0,0,0,0,0,0,0, 1,1,1,1,1,1,1,1, 2,2,2,2,2,2,2,
        3,3,3,3,3,3, 4,4,4,4,4, 5,5,5,5, 6,6,6, 7,7, 8};
    static constexpr int PB[NPAIR] = {
        0,1,2,3,4,5,6,7,8, 1,2,3,4,5,6,7,8, 2,3,4,5,6,7,8,
        3,4,5,6,7,8, 4,5,6,7,8, 5,6,7,8, 6,7,8, 7,8, 8};

    const int gid  = blockIdx.x * THREADS + threadIdx.x;
    const int atom = gid >> 5;
    const int c4   = gid & 31;
    const size_t base = (size_t)atom * (S9 * NFEAT) + (size_t)c4 * 4;

    f4 xv[S9];
    #pragma unroll
    for (int s = 0; s < S9; ++s)
        xv[s] = *(const f4*)(x + base + (size_t)s * NFEAT);

    f4 acc[S9];
    #pragma unroll
    for (int k = 0; k < S9; ++k) acc[k] = (f4)0.f;

    #pragma unroll
    for (int p = 0; p < NPAIR; ++p) {
        const f4 wA = *(const f4*)(W + p * WSTRIDE);       // k = 0..3
        const f4 wB = *(const f4*)(W + p * WSTRIDE + 4);   // k = 4..7
        const f4 wC = *(const f4*)(W + p * WSTRIDE + 8);   // k = 8 (+pad)
        const f4 prod = xv[PA[p]] * xv[PB[p]];
        acc[0] = acc[0] + wA[0] * prod;
        acc[1] = acc[1] + wA[1] * prod;
        acc[2] = acc[2] + wA[2] * prod;
        acc[3] = acc[3] + wA[3] * prod;
        acc[4] = acc[4] + wB[0] * prod;
        acc[5] = acc[5] + wB[1] * prod;
        acc[6] = acc[6] + wB[2] * prod;
        acc[7] = acc[7] + wB[3] * prod;
        acc[8] = acc[8] + wC[0] * prod;
    }

    #pragma unroll
    for (int k = 0; k < S9; ++k)
        stream_store_f4(y + base + (size_t)k * NFEAT, acc[k]);
}

extern "C" void kernel_launch(void* const* d_in, const int* in_sizes, int n_in,
                              void* d_out, int out_size, void* d_ws, size_t ws_size,
                              hipStream_t stream) {
    const float* x       = (const float*)d_in[0];
    const float* weight  = (const float*)d_in[1];
    const float* cg_vals = (const float*)d_in[2];
    const int* idx_1     = (const int*)d_in[3];
    const int* idx_2     = (const int*)d_in[4];
    const int* idx_out   = (const int*)d_in[5];
    const int* widx_1    = (const int*)d_in[6];
    const int* widx_2    = (const int*)d_in[7];
    float* y             = (float*)d_out;
    float* W             = (float*)d_ws;

    const int nnz     = in_sizes[2];
    const int n_atoms = in_sizes[0] / (S9 * NFEAT);       // 32000

    so3_prep_kernel<<<1, THREADS, 0, stream>>>(weight, cg_vals, idx_1, idx_2,
                                               idx_out, widx_1, widx_2, nnz, W);

    const int total = n_atoms * 32;                        // one thread per (atom, f4)
    so3_main_kernel<<<total / THREADS, THREADS, 0, stream>>>(x, W, y);
}